// Round 2
// baseline (1039.601 us; speedup 1.0000x reference)
//
#include <hip/hip_runtime.h>

typedef __attribute__((ext_vector_type(2))) float f2v;
typedef __attribute__((ext_vector_type(4))) float f4v;
typedef __attribute__((ext_vector_type(8))) short s8v;

#define YP 40  // pitch in shorts for 32-feature (64 B) rows: 80 B stride, 20-bank walk (2-way, free)

static __device__ __forceinline__ short f2bf_rne(float f) {
    unsigned u = __builtin_bit_cast(unsigned, f);
    unsigned r = (u + 0x7FFFu + ((u >> 16) & 1u)) >> 16;  // RNE
    return (short)r;
}

// round-to-nearest (ties-up) pack of 2 floats -> 2 bf16 in one dword; 3 VALU
static __device__ __forceinline__ unsigned pack_bf16_rn(float x, float y) {
    unsigned a = __builtin_bit_cast(unsigned, x) + 0x8000u;
    unsigned b = __builtin_bit_cast(unsigned, y) + 0x8000u;
    return __builtin_amdgcn_perm(b, a, 0x07060302u);  // {b[31:16], a[31:16]}
}

// W[3][256][256] (k,f,o) fp32 -> Wt[3][256][256] (k,o,f) bf16 via LDS tile transpose
__global__ void wt_transpose_kernel(const float* __restrict__ W, short* __restrict__ Wt) {
    __shared__ short t[64][65];
    int k  = blockIdx.x >> 4;
    int r  = blockIdx.x & 15;
    int f0 = (r >> 2) << 6;
    int o0 = (r & 3) << 6;
    const float* Wk  = W  + k * 65536;
    short*       Wtk = Wt + k * 65536;
    #pragma unroll
    for (int e = 0; e < 16; e++) {
        int idx = e * 256 + threadIdx.x;
        int f = idx >> 6, o = idx & 63;
        t[f][o] = f2bf_rne(Wk[(f0 + f) * 256 + o0 + o]);
    }
    __syncthreads();
    #pragma unroll
    for (int e = 0; e < 16; e++) {
        int idx = e * 256 + threadIdx.x;
        int o = idx >> 6, f = idx & 63;
        Wtk[(o0 + o) * 256 + f0 + f] = t[f][o];
    }
}

// Fused: Y_k = A_k x (fp32 reg aggregation) -> bf16 LDS (dbuf) -> MFMA vs Wt -> out + bias
__global__ __launch_bounds__(256, 2) void gconv_kernel(
        const float* __restrict__ x, const short* __restrict__ Wt,
        const float* __restrict__ adj, const float* __restrict__ bias,
        float* __restrict__ out) {
    __shared__ __align__(16) short Ys[2][272 * YP];  // 2 x 21760 B
    __shared__ __align__(16) short Ws[2][128 * YP];  // 2 x 10240 B   (total 64000 B)

    const int bx   = blockIdx.x;
    const int nh   = (bx >> 3) & 1;              // N-half; (g,0)/(g,1) 8 apart -> same XCD
    const int g    = (bx >> 4) * 8 + (bx & 7);   // batch group 0..1023 (16 batches)
    const int tid  = threadIdx.x;
    const int bb   = tid >> 4;                   // local batch 0..15
    const int fq   = tid & 15;                   // feature-pair idx within 32-chunk
    const int o0   = nh << 7;
    const int wave = tid >> 6;
    const int lane = tid & 63;
    const int mn   = lane & 15;
    const int quad = lane >> 4;

    const float* xg = x   + (size_t)g * (272 * 256);
    float*       og = out + (size_t)g * (272 * 256);

    f4v acc[17][2];
    #pragma unroll
    for (int nt = 0; nt < 2; nt++) {
        float bv = bias[o0 + wave * 32 + nt * 16 + mn];
        #pragma unroll
        for (int mt = 0; mt < 17; mt++) acc[mt][nt] = (f4v){bv, bv, bv, bv};
    }

    int it = 0;
    for (int c = 0; c < 8; ++c) {
        const int fc0 = c << 5;
        f2v xq[17];
        #pragma unroll
        for (int j = 0; j < 17; j++)
            xq[j] = *(const f2v*)(xg + (bb * 17 + j) * 256 + fc0 + fq * 2);

        #pragma unroll
        for (int k = 0; k < 3; ++k, ++it) {
            const int p = it & 1;
            short* Ysp = Ys[p];
            short* Wsp = Ws[p];
            // ---- aggregation: one k's 17 rows, fp32 in regs, RN-pack to bf16 ----
            #pragma unroll
            for (int i = 0; i < 17; i++) {
                f2v a = {0.f, 0.f};
                if (k == 0) {
                    a = adj[i * 17 + i] * xq[i];
                } else if (k == 1) {
                    #pragma unroll
                    for (int j = i + 1; j < 17; j++) a += adj[i * 17 + j] * xq[j];
                } else {
                    #pragma unroll
                    for (int j = 0; j < i; j++) a += adj[i * 17 + j] * xq[j];
                }
                *(unsigned*)(Ysp + (bb * 17 + i) * YP + fq * 2) = pack_bf16_rn(a.x, a.y);
            }
            // ---- stage Wt[k][o0..o0+128][fc0..fc0+32] -> Ws[p] ----
            const short* Wtk = Wt + k * 65536;
            #pragma unroll
            for (int e = 0; e < 2; e++) {
                int idx = e * 256 + tid;
                int row = idx >> 2, seg = idx & 3;
                *(s8v*)(Wsp + row * YP + seg * 8) =
                    *(const s8v*)(Wtk + (o0 + row) * 256 + fc0 + seg * 8);
            }
            __syncthreads();
            // ---- MFMA: 17 M-tiles x 2 N-tiles, K=32 ----
            s8v bf0 = *(const s8v*)(Wsp + (wave * 32 + mn) * YP + quad * 8);
            s8v bf1 = *(const s8v*)(Wsp + (wave * 32 + 16 + mn) * YP + quad * 8);
            #pragma unroll
            for (int mt = 0; mt < 17; mt++) {
                s8v af = *(const s8v*)(Ysp + (mt * 16 + mn) * YP + quad * 8);
                acc[mt][0] = __builtin_amdgcn_mfma_f32_16x16x32_bf16(af, bf0, acc[mt][0], 0, 0, 0);
                acc[mt][1] = __builtin_amdgcn_mfma_f32_16x16x32_bf16(af, bf1, acc[mt][1], 0, 0, 0);
            }
            // no second barrier: buf p is next written at it+2, after the it+1 barrier,
            // by which point every wave's MFMA(it) has completed (program order)
        }
    }

    // ---- epilogue: C/D layout col=lane&15, row=quad*4+reg ----
    #pragma unroll
    for (int mt = 0; mt < 17; mt++) {
        #pragma unroll
        for (int nt = 0; nt < 2; nt++) {
            int o  = o0 + wave * 32 + nt * 16 + mn;
            int rb = mt * 16 + quad * 4;
            #pragma unroll
            for (int rg = 0; rg < 4; rg++)
                og[(rb + rg) * 256 + o] = acc[mt][nt][rg];
        }
    }
}

extern "C" void kernel_launch(void* const* d_in, const int* in_sizes, int n_in,
                              void* d_out, int out_size, void* d_ws, size_t ws_size,
                              hipStream_t stream) {
    const float* x    = (const float*)d_in[0];
    const float* W    = (const float*)d_in[1];
    const float* adj  = (const float*)d_in[2];
    const float* bias = (const float*)d_in[3];
    float* out = (float*)d_out;
    short* Wt  = (short*)d_ws;  // 3*256*256 bf16 = 393 KB

    hipLaunchKernelGGL(wt_transpose_kernel, dim3(48), dim3(256), 0, stream, W, Wt);
    hipLaunchKernelGGL(gconv_kernel, dim3(2048), dim3(256), 0, stream,
                       x, Wt, adj, bias, out);
}